// Round 12
// baseline (152.226 us; speedup 1.0000x reference)
//
#include <hip/hip_runtime.h>
#include <math.h>

// Depth collapses to d=0 (x[:, :, 0:1] slicing): conv1d -> w[3]*xi+b,
// scan at d=0 -> hs[0]=BX[0] (A_log unused), y = xi*(delta*sum(B*C)+D).
//
// Round-12: r11 structure (151.2us best: prep1(L0-only), conv0+prep(L1),
// ssm0, conv1, ssm1) + ssm out_proj tail restructured m-major:
//  - old tail: each thread 1.5 (pl,m) pairs x 192 scalar wpT loads = 288
//    loads/thread, reuse x1.5, ~288KB/block vs 73KB table, L2-latency
//    exposed at 1.1 blocks/CU.
//  - new tail: 192 threads = (c-half, m); each loads wpT[c][m] ONCE per c
//    (96 loads/thread, coalesced) and feeds all 4 pixels (4x FMA reuse);
//    3KB LDS partial-combine; final add-residual-store unchanged.
// conv_k / prep / phase-1 ssm byte-identical to r11.
#define NB   2
#define CM   96      // D_MODEL
#define CI   192     // D_INNER
#define CO   384     // 2*D_INNER
#define HP   24
#define WP   24
#define PX   576
#define DTR  6
#define NDBC 38
#define CSPLIT 8
#define CCH  12      // input channels per conv chunk (96/CSPLIT)
#define IPW_L (CO*CM*9)   // 331776 floats per layer
#define WQB_L (CM*CO*8)   // ushorts per layer
#define WRB_L (CM*CO)
#define WPT_L (CI*CM)
#define NPREP (IPW_L + WPT_L)   // 350208 elems per layer

__device__ __forceinline__ float siluf(float x){ return x / (1.f + expf(-x)); }
__device__ __forceinline__ float softplusf(float x){ return x > 20.f ? x : log1pf(expf(x)); }
__device__ __forceinline__ unsigned short f2bf(float f){
    unsigned u = __float_as_uint(f);
    return (unsigned short)((u + 0x7fffu + ((u >> 16) & 1u)) >> 16);
}
__device__ __forceinline__ float bflo(unsigned u){ return __uint_as_float(u << 16); }
__device__ __forceinline__ float bfhi(unsigned u){ return __uint_as_float(u & 0xffff0000u); }

// one layer's prep work, element idx in [0, NPREP)
__device__ __forceinline__ void prep_elem(
    int idx, const float* __restrict__ ipw, const float* __restrict__ opw,
    unsigned short* __restrict__ wQb, unsigned short* __restrict__ wRb,
    float* __restrict__ wpT)
{
    if (idx < IPW_L){
        int o = idx / (CM*9);
        int r2 = idx % (CM*9);
        int c = r2 / 9;
        int k = r2 % 9;
        unsigned short v = f2bf(ipw[idx]);
        if (k < 8) wQb[((c*CO + o)<<3) + k] = v;
        else       wRb[c*CO + o] = v;
    } else {
        int j = idx - IPW_L;
        int c = j / CM, m = j % CM;
        wpT[c*CM + m] = opw[(long)m*CI + c];
    }
}

// ---- prep (layer 0 only): 1368 blocks x 256 = 350208 threads
__global__ void prep1_k(const float* __restrict__ ipw, const float* __restrict__ opw,
                        unsigned short* __restrict__ wQb, unsigned short* __restrict__ wRb,
                        float* __restrict__ wpT){
    int idx = blockIdx.x*256 + threadIdx.x;
    if (idx < NPREP) prep_elem(idx, ipw, opw, wQb, wRb, wpT);
}

// ---- conv: fused rmsnorm + 3x3 conv (pad 1), bf16 weights, fp32 accum.
// grid (NB*HP, 2 og2-halves, CSPLIT [+1 prep slice for layer 0]), block 256.
// z==CSPLIT blocks run layer-1 prep (outputs consumed by later dispatches).
// conv blocks: 3 o-chunks of 64, c-loop outermost, double-buffered.
// acc layout: [cs][n][px][o]
__global__ __launch_bounds__(256, 3) void conv_k(
    const float* __restrict__ x, long nStr, long cStr,
    const float* __restrict__ nw,
    const unsigned short* __restrict__ wQb, const unsigned short* __restrict__ wRb,
    float* __restrict__ acc,
    const float* __restrict__ ipw1, const float* __restrict__ opw1,
    unsigned short* __restrict__ wQb1, unsigned short* __restrict__ wRb1,
    float* __restrict__ wpT1)
{
    __shared__ float hs[CCH][3][28];   // 28-wide rows: every (c,j) row base 16B-aligned
    __shared__ float scl[CCH][3];
    int bx  = blockIdx.x;
    int og2 = blockIdx.y;              // 0..1 -> outputs og2*192 .. +192
    int cs  = blockIdx.z;
    int tid = threadIdx.x;

    // ---- prep-role blocks (layer-0 launch only): write layer-1 weights
    if (cs == CSPLIT){
        int base = (bx + NB*HP*og2)*256 + tid;      // 0..24575
        for (int idx = base; idx < NPREP; idx += NB*HP*2*256)
            prep_elem(idx, ipw1, opw1, wQb1, wRb1, wpT1);
        return;
    }

    int n  = bx / HP, hh = bx % HP;
    int c0 = cs*CCH;

    if (tid < CCH*3){
        int c = tid/3, j = tid%3;
        int row = hh + j - 1;
        float s = 0.f;
        if (row >= 0 && row < HP){
            const float4* xp4 = (const float4*)(x + (long)n*nStr + (long)(c0+c)*cStr + row*WP);
            #pragma unroll
            for (int w4 = 0; w4 < WP/4; w4++){
                float4 v = xp4[w4];
                s += v.x*v.x + v.y*v.y + v.z*v.z + v.w*v.w;
            }
            s = rsqrtf(s*(1.0f/WP) + 1e-5f) * nw[c0+c];
        }
        scl[c][j] = s;
    }
    __syncthreads();

    for (int idx = tid; idx < CCH*3*28; idx += 256){
        int c = idx/84; int rem = idx%84; int j = rem/28; int wc = rem%28;
        int row = hh + j - 1;
        float v = 0.f;
        if (row >= 0 && row < HP && wc >= 1 && wc <= WP)
            v = x[(long)n*nStr + (long)(c0+c)*cStr + row*WP + (wc-1)] * scl[c][j];
        hs[c][j][wc] = v;
    }
    __syncthreads();

    int ol = tid & 63;
    int obase = og2*192 + ol;          // + oc*64, oc in 0..2
    int x0 = (tid >> 6) * 6;           // even -> 8B-aligned float2 loads
    float a0[3][6] = {{0,0,0,0,0,0},{0,0,0,0,0,0},{0,0,0,0,0,0}};
    const uint4* wq4 = (const uint4*)wQb;

    // ---- software pipeline: prefetch c=0
    uint4 nw4[3]; unsigned short nw8[3];
    float2 nh[3][4];
    {
        int cg = c0;
        #pragma unroll
        for (int oc = 0; oc < 3; oc++){
            nw4[oc] = wq4[cg*CO + obase + oc*64];
            nw8[oc] = wRb[cg*CO + obase + oc*64];
        }
        #pragma unroll
        for (int j = 0; j < 3; j++)
            #pragma unroll
            for (int i = 0; i < 4; i++)
                nh[j][i] = *(const float2*)(&hs[0][j][x0] + 2*i);
    }

    for (int c = 0; c < CCH; c++){
        // rotate prefetched -> current
        uint4 cw4[3]; unsigned short cw8[3]; float2 ch[3][4];
        #pragma unroll
        for (int oc = 0; oc < 3; oc++){ cw4[oc] = nw4[oc]; cw8[oc] = nw8[oc]; }
        #pragma unroll
        for (int j = 0; j < 3; j++)
            #pragma unroll
            for (int i = 0; i < 4; i++) ch[j][i] = nh[j][i];

        // issue c+1 loads (hidden under this c's FMA burst)
        if (c + 1 < CCH){
            int cg = c0 + c + 1;
            #pragma unroll
            for (int oc = 0; oc < 3; oc++){
                nw4[oc] = wq4[cg*CO + obase + oc*64];
                nw8[oc] = wRb[cg*CO + obase + oc*64];
            }
            #pragma unroll
            for (int j = 0; j < 3; j++)
                #pragma unroll
                for (int i = 0; i < 4; i++)
                    nh[j][i] = *(const float2*)(&hs[c+1][j][x0] + 2*i);
        }

        float r0v[8], r1v[8], r2v[8];
        #pragma unroll
        for (int i = 0; i < 4; i++){
            r0v[2*i] = ch[0][i].x; r0v[2*i+1] = ch[0][i].y;
            r1v[2*i] = ch[1][i].x; r1v[2*i+1] = ch[1][i].y;
            r2v[2*i] = ch[2][i].x; r2v[2*i+1] = ch[2][i].y;
        }
        #pragma unroll
        for (int oc = 0; oc < 3; oc++){
            uint4 wv = cw4[oc];
            float w0 = bflo(wv.x), w1 = bfhi(wv.x);
            float w2 = bflo(wv.y), w3 = bfhi(wv.y);
            float w4 = bflo(wv.z), w5 = bfhi(wv.z);
            float w6 = bflo(wv.w), w7 = bfhi(wv.w);
            float w8 = bflo((unsigned)cw8[oc]);
            #pragma unroll
            for (int p = 0; p < 6; p++){
                a0[oc][p] += w0*r0v[p] + w1*r0v[p+1] + w2*r0v[p+2]
                           + w3*r1v[p] + w4*r1v[p+1] + w5*r1v[p+2]
                           + w6*r2v[p] + w7*r2v[p+1] + w8*r2v[p+2];
            }
        }
    }

    #pragma unroll
    for (int oc = 0; oc < 3; oc++){
        float* ap = acc + ((long)(cs*NB + n)*PX + hh*WP + x0)*CO + obase + oc*64;
        #pragma unroll
        for (int p = 0; p < 6; p++) ap[p*CO] = a0[oc][p];
    }
}

// ---- ssm: sum partials -> conv1d tap + SiLU gates -> x_proj/dt/BC -> gate ->
//           out_proj + residual. block 256 = 4 waves = 4 pixels; grid NB*PX/4.
// Tail is m-major: thread (c-half, m) loads wpT[c][m] once per c and feeds
// all 4 pixels (4x reuse); LDS partial-combine.
__global__ __launch_bounds__(256) void ssmproj_k(
    const float* __restrict__ acc,
    const float* __restrict__ c1w, const float* __restrict__ c1b,
    const float* __restrict__ xpw, const float* __restrict__ dtw,
    const float* __restrict__ dtb, const float* __restrict__ Dp,
    const float* __restrict__ wpT,
    const float* __restrict__ xres, long nStrR, long cStrR,
    float* __restrict__ dst)
{
    __shared__ float gl[4][CI];
    __shared__ float part[2][4][CM];   // 3KB partials: [c-half][pl][m]
    int wave = threadIdx.x >> 6, lane = threadIdx.x & 63;
    int p0 = blockIdx.x*4;
    int p  = p0 + wave;
    int n  = p / PX, px = p % PX;

    float xi[3], sz[3];
    #pragma unroll
    for (int t = 0; t < 3; t++){
        int c = lane + 64*t;
        float xr = 0.f, zr = 0.f;
        #pragma unroll
        for (int q = 0; q < CSPLIT; q++){
            const float* ap = acc + ((long)(q*NB + n)*PX + px)*CO;
            xr += ap[c]; zr += ap[CI + c];
        }
        xi[t] = siluf(xr*c1w[c*4 + 3] + c1b[c]);
        sz[t] = siluf(zr);
    }

    float dbc[NDBC];
    #pragma unroll
    for (int j = 0; j < NDBC; j++){
        float s = 0.f;
        #pragma unroll
        for (int t = 0; t < 3; t++) s += xi[t]*xpw[j*CI + lane + 64*t];
        dbc[j] = s;
    }
    #pragma unroll
    for (int step = 1; step < 64; step <<= 1){
        #pragma unroll
        for (int j = 0; j < NDBC; j++) dbc[j] += __shfl_xor(dbc[j], step, 64);
    }
    float BC = 0.f;
    #pragma unroll
    for (int s = 0; s < 16; s++) BC += dbc[6+s]*dbc[22+s];

    #pragma unroll
    for (int t = 0; t < 3; t++){
        int c = lane + 64*t;
        float dl = dtb[c];
        #pragma unroll
        for (int r = 0; r < DTR; r++) dl += dbc[r]*dtw[c*DTR + r];
        dl = softplusf(dl);
        gl[wave][c] = xi[t]*(dl*BC + Dp[c])*sz[t];
    }
    __syncthreads();

    // ---- out_proj partials: threads 0..191 = (c-half, m). Each wpT[c][m]
    // load (coalesced across lanes) feeds 4 pixels' FMAs.
    if (threadIdx.x < 2*CM){
        int ch2 = threadIdx.x / CM;        // 0..1 -> c in [ch2*96, ch2*96+96)
        int m   = threadIdx.x % CM;
        const float* wp = wpT + m;
        float s0 = 0.f, s1 = 0.f, s2 = 0.f, s3 = 0.f;
        int cbeg = ch2*96, cend = cbeg + 96;
        #pragma unroll 4
        for (int c = cbeg; c < cend; c++){
            float w = wp[(long)c*CM];
            s0 += gl[0][c]*w;
            s1 += gl[1][c]*w;
            s2 += gl[2][c]*w;
            s3 += gl[3][c]*w;
        }
        part[ch2][0][m] = s0;
        part[ch2][1][m] = s1;
        part[ch2][2][m] = s2;
        part[ch2][3][m] = s3;
    }
    __syncthreads();

    for (int idx = threadIdx.x; idx < 4*CM; idx += 256){
        int pl = idx / CM, m = idx % CM;
        int pp = p0 + pl;
        int nn = pp / PX, ppx = pp % PX;
        float s = part[0][pl][m] + part[1][pl][m];
        s += xres[(long)nn*nStrR + (long)m*cStrR + ppx];
        dst[(nn*CM + m)*PX + ppx] = s;
    }
}

extern "C" void kernel_launch(void* const* d_in, const int* in_sizes, int n_in,
                              void* d_out, int out_size, void* d_ws, size_t ws_size,
                              hipStream_t stream) {
    const float* x_in = (const float*)d_in[0];   // (2,96,8,24,24)
    const float* ipw  = (const float*)d_in[1];   // (2,384,96,1,3,3)
    const float* c1w  = (const float*)d_in[2];   // (2,192,1,4,1,1)
    const float* c1b  = (const float*)d_in[3];   // (2,192)
    const float* xpw  = (const float*)d_in[4];   // (2,38,192)
    const float* dtw  = (const float*)d_in[5];   // (2,192,6)
    const float* dtb  = (const float*)d_in[6];   // (2,192)
    // d_in[7] = A_log: unused at depth 0 (multiplies h[-1]=0)
    const float* Dp   = (const float*)d_in[8];   // (2,192)
    const float* opw  = (const float*)d_in[9];   // (2,96,192)
    const float* nw   = (const float*)d_in[10];  // (2,1,96,1,1,1)

    char* ws = (char*)d_ws;
    unsigned short* wQb = (unsigned short*)ws;              // 2*294912 ush = 1179648 B
    unsigned short* wRb = wQb + 2*WQB_L;                    // 2*36864 ush  = 147456 B
    float* wpT = (float*)(wRb + 2*WRB_L);                   // 2*18432 f    = 147456 B
    float* acc = wpT + 2*WPT_L;                             // 8*2*576*384 f = 14155776 B
    float* x1  = acc + (long)CSPLIT*NB*PX*CO;               // 110592 f

    // ---- prep layer 0 only
    prep1_k<<<(NPREP + 255)/256, 256, 0, stream>>>(ipw, opw, wQb, wRb, wpT);

    // ---- layer 0 conv (z=8 slice additionally preps layer-1 weights,
    //      consumed only by the later conv1/ssm1 dispatches)
    conv_k<<<dim3(NB*HP, 2, CSPLIT+1), 256, 0, stream>>>(
        x_in, 96L*8*PX, 8L*PX, nw, wQb, wRb, acc,
        ipw + IPW_L, opw + CM*CI, wQb + WQB_L, wRb + WRB_L, wpT + WPT_L);
    ssmproj_k<<<NB*PX/4, 256, 0, stream>>>(
        acc, c1w, c1b, xpw, dtw, dtb, Dp, wpT,
        x_in, 96L*8*PX, 8L*PX, x1);

    // ---- layer 1 (input x1 packed (2,96,24,24); writes final output)
    conv_k<<<dim3(NB*HP, 2, CSPLIT), 256, 0, stream>>>(
        x1, 96L*PX, (long)PX, nw + CM, wQb + WQB_L, wRb + WRB_L, acc,
        nullptr, nullptr, nullptr, nullptr, nullptr);
    ssmproj_k<<<NB*PX/4, 256, 0, stream>>>(
        acc, c1w + CI*4, c1b + CI, xpw + NDBC*CI, dtw + CI*DTR, dtb + CI, Dp + CI, wpT + WPT_L,
        x1, 96L*PX, (long)PX, (float*)d_out);
}

// Round 13
// 150.624 us; speedup vs baseline: 1.0106x; 1.0106x over previous
//
#include <hip/hip_runtime.h>
#include <math.h>

// Depth collapses to d=0 (x[:, :, 0:1] slicing): conv1d -> w[3]*xi+b,
// scan at d=0 -> hs[0]=BX[0] (A_log unused), y = xi*(delta*sum(B*C)+D).
//
// Round-13 = exact revert to r11 (151.2us session best).
// Structure: 5 dispatches (prep1 L0-only, conv0+prep(L1) piggyback,
// ssm0, conv1, ssm1).
//  - conv: og2-collapsed (3 o-chunks/block, c-loop outermost),
//    software-pipelined c-loop (r9), launch_bounds(256,3).
//  - ssm: r9's 38-value butterfly + pl-major out_proj tail
//    (r10 split-reduction and r12 m-major tail both falsified: ±0).
//  - prep split: L0 in prep1_k; L1 prepped by conv0's z=8 grid slice,
//    consumed only by LATER dispatches (stream-ordered, no fences).
// Falsified levers (do not retry): dispatch-count reduction (r3/r7/r8),
// intra-kernel cross-block dataflow (r1 spin, r5 fence = serialized L2
// flushes on 8 XCDs), CSPLIT!=8 (r2), big-LDS conv (r7: occupancy cliff).
#define NB   2
#define CM   96      // D_MODEL
#define CI   192     // D_INNER
#define CO   384     // 2*D_INNER
#define HP   24
#define WP   24
#define PX   576
#define DTR  6
#define NDBC 38
#define CSPLIT 8
#define CCH  12      // input channels per conv chunk (96/CSPLIT)
#define IPW_L (CO*CM*9)   // 331776 floats per layer
#define WQB_L (CM*CO*8)   // ushorts per layer
#define WRB_L (CM*CO)
#define WPT_L (CI*CM)
#define NPREP (IPW_L + WPT_L)   // 350208 elems per layer

__device__ __forceinline__ float siluf(float x){ return x / (1.f + expf(-x)); }
__device__ __forceinline__ float softplusf(float x){ return x > 20.f ? x : log1pf(expf(x)); }
__device__ __forceinline__ unsigned short f2bf(float f){
    unsigned u = __float_as_uint(f);
    return (unsigned short)((u + 0x7fffu + ((u >> 16) & 1u)) >> 16);
}
__device__ __forceinline__ float bflo(unsigned u){ return __uint_as_float(u << 16); }
__device__ __forceinline__ float bfhi(unsigned u){ return __uint_as_float(u & 0xffff0000u); }

// one layer's prep work, element idx in [0, NPREP)
__device__ __forceinline__ void prep_elem(
    int idx, const float* __restrict__ ipw, const float* __restrict__ opw,
    unsigned short* __restrict__ wQb, unsigned short* __restrict__ wRb,
    float* __restrict__ wpT)
{
    if (idx < IPW_L){
        int o = idx / (CM*9);
        int r2 = idx % (CM*9);
        int c = r2 / 9;
        int k = r2 % 9;
        unsigned short v = f2bf(ipw[idx]);
        if (k < 8) wQb[((c*CO + o)<<3) + k] = v;
        else       wRb[c*CO + o] = v;
    } else {
        int j = idx - IPW_L;
        int c = j / CM, m = j % CM;
        wpT[c*CM + m] = opw[(long)m*CI + c];
    }
}

// ---- prep (layer 0 only): 1368 blocks x 256 = 350208 threads
__global__ void prep1_k(const float* __restrict__ ipw, const float* __restrict__ opw,
                        unsigned short* __restrict__ wQb, unsigned short* __restrict__ wRb,
                        float* __restrict__ wpT){
    int idx = blockIdx.x*256 + threadIdx.x;
    if (idx < NPREP) prep_elem(idx, ipw, opw, wQb, wRb, wpT);
}

// ---- conv: fused rmsnorm + 3x3 conv (pad 1), bf16 weights, fp32 accum.
// grid (NB*HP, 2 og2-halves, CSPLIT [+1 prep slice for layer 0]), block 256.
// z==CSPLIT blocks run layer-1 prep (outputs consumed by later dispatches).
// conv blocks: 3 o-chunks of 64, c-loop outermost, double-buffered.
// acc layout: [cs][n][px][o]
__global__ __launch_bounds__(256, 3) void conv_k(
    const float* __restrict__ x, long nStr, long cStr,
    const float* __restrict__ nw,
    const unsigned short* __restrict__ wQb, const unsigned short* __restrict__ wRb,
    float* __restrict__ acc,
    const float* __restrict__ ipw1, const float* __restrict__ opw1,
    unsigned short* __restrict__ wQb1, unsigned short* __restrict__ wRb1,
    float* __restrict__ wpT1)
{
    __shared__ float hs[CCH][3][28];   // 28-wide rows: every (c,j) row base 16B-aligned
    __shared__ float scl[CCH][3];
    int bx  = blockIdx.x;
    int og2 = blockIdx.y;              // 0..1 -> outputs og2*192 .. +192
    int cs  = blockIdx.z;
    int tid = threadIdx.x;

    // ---- prep-role blocks (layer-0 launch only): write layer-1 weights
    if (cs == CSPLIT){
        int base = (bx + NB*HP*og2)*256 + tid;      // 0..24575
        for (int idx = base; idx < NPREP; idx += NB*HP*2*256)
            prep_elem(idx, ipw1, opw1, wQb1, wRb1, wpT1);
        return;
    }

    int n  = bx / HP, hh = bx % HP;
    int c0 = cs*CCH;

    if (tid < CCH*3){
        int c = tid/3, j = tid%3;
        int row = hh + j - 1;
        float s = 0.f;
        if (row >= 0 && row < HP){
            const float4* xp4 = (const float4*)(x + (long)n*nStr + (long)(c0+c)*cStr + row*WP);
            #pragma unroll
            for (int w4 = 0; w4 < WP/4; w4++){
                float4 v = xp4[w4];
                s += v.x*v.x + v.y*v.y + v.z*v.z + v.w*v.w;
            }
            s = rsqrtf(s*(1.0f/WP) + 1e-5f) * nw[c0+c];
        }
        scl[c][j] = s;
    }
    __syncthreads();

    for (int idx = tid; idx < CCH*3*28; idx += 256){
        int c = idx/84; int rem = idx%84; int j = rem/28; int wc = rem%28;
        int row = hh + j - 1;
        float v = 0.f;
        if (row >= 0 && row < HP && wc >= 1 && wc <= WP)
            v = x[(long)n*nStr + (long)(c0+c)*cStr + row*WP + (wc-1)] * scl[c][j];
        hs[c][j][wc] = v;
    }
    __syncthreads();

    int ol = tid & 63;
    int obase = og2*192 + ol;          // + oc*64, oc in 0..2
    int x0 = (tid >> 6) * 6;           // even -> 8B-aligned float2 loads
    float a0[3][6] = {{0,0,0,0,0,0},{0,0,0,0,0,0},{0,0,0,0,0,0}};
    const uint4* wq4 = (const uint4*)wQb;

    // ---- software pipeline: prefetch c=0
    uint4 nw4[3]; unsigned short nw8[3];
    float2 nh[3][4];
    {
        int cg = c0;
        #pragma unroll
        for (int oc = 0; oc < 3; oc++){
            nw4[oc] = wq4[cg*CO + obase + oc*64];
            nw8[oc] = wRb[cg*CO + obase + oc*64];
        }
        #pragma unroll
        for (int j = 0; j < 3; j++)
            #pragma unroll
            for (int i = 0; i < 4; i++)
                nh[j][i] = *(const float2*)(&hs[0][j][x0] + 2*i);
    }

    for (int c = 0; c < CCH; c++){
        // rotate prefetched -> current
        uint4 cw4[3]; unsigned short cw8[3]; float2 ch[3][4];
        #pragma unroll
        for (int oc = 0; oc < 3; oc++){ cw4[oc] = nw4[oc]; cw8[oc] = nw8[oc]; }
        #pragma unroll
        for (int j = 0; j < 3; j++)
            #pragma unroll
            for (int i = 0; i < 4; i++) ch[j][i] = nh[j][i];

        // issue c+1 loads (hidden under this c's FMA burst)
        if (c + 1 < CCH){
            int cg = c0 + c + 1;
            #pragma unroll
            for (int oc = 0; oc < 3; oc++){
                nw4[oc] = wq4[cg*CO + obase + oc*64];
                nw8[oc] = wRb[cg*CO + obase + oc*64];
            }
            #pragma unroll
            for (int j = 0; j < 3; j++)
                #pragma unroll
                for (int i = 0; i < 4; i++)
                    nh[j][i] = *(const float2*)(&hs[c+1][j][x0] + 2*i);
        }

        float r0v[8], r1v[8], r2v[8];
        #pragma unroll
        for (int i = 0; i < 4; i++){
            r0v[2*i] = ch[0][i].x; r0v[2*i+1] = ch[0][i].y;
            r1v[2*i] = ch[1][i].x; r1v[2*i+1] = ch[1][i].y;
            r2v[2*i] = ch[2][i].x; r2v[2*i+1] = ch[2][i].y;
        }
        #pragma unroll
        for (int oc = 0; oc < 3; oc++){
            uint4 wv = cw4[oc];
            float w0 = bflo(wv.x), w1 = bfhi(wv.x);
            float w2 = bflo(wv.y), w3 = bfhi(wv.y);
            float w4 = bflo(wv.z), w5 = bfhi(wv.z);
            float w6 = bflo(wv.w), w7 = bfhi(wv.w);
            float w8 = bflo((unsigned)cw8[oc]);
            #pragma unroll
            for (int p = 0; p < 6; p++){
                a0[oc][p] += w0*r0v[p] + w1*r0v[p+1] + w2*r0v[p+2]
                           + w3*r1v[p] + w4*r1v[p+1] + w5*r1v[p+2]
                           + w6*r2v[p] + w7*r2v[p+1] + w8*r2v[p+2];
            }
        }
    }

    #pragma unroll
    for (int oc = 0; oc < 3; oc++){
        float* ap = acc + ((long)(cs*NB + n)*PX + hh*WP + x0)*CO + obase + oc*64;
        #pragma unroll
        for (int p = 0; p < 6; p++) ap[p*CO] = a0[oc][p];
    }
}

// ---- ssm: sum partials -> conv1d tap + SiLU gates -> x_proj/dt/BC -> gate ->
//               out_proj + residual. block 256 = 4 waves = 4 pixels; grid NB*PX/4.
__global__ __launch_bounds__(256) void ssmproj_k(
    const float* __restrict__ acc,
    const float* __restrict__ c1w, const float* __restrict__ c1b,
    const float* __restrict__ xpw, const float* __restrict__ dtw,
    const float* __restrict__ dtb, const float* __restrict__ Dp,
    const float* __restrict__ wpT,
    const float* __restrict__ xres, long nStrR, long cStrR,
    float* __restrict__ dst)
{
    __shared__ float gl[4][CI];
    int wave = threadIdx.x >> 6, lane = threadIdx.x & 63;
    int p0 = blockIdx.x*4;
    int p  = p0 + wave;
    int n  = p / PX, px = p % PX;

    float xi[3], sz[3];
    #pragma unroll
    for (int t = 0; t < 3; t++){
        int c = lane + 64*t;
        float xr = 0.f, zr = 0.f;
        #pragma unroll
        for (int q = 0; q < CSPLIT; q++){
            const float* ap = acc + ((long)(q*NB + n)*PX + px)*CO;
            xr += ap[c]; zr += ap[CI + c];
        }
        xi[t] = siluf(xr*c1w[c*4 + 3] + c1b[c]);
        sz[t] = siluf(zr);
    }

    float dbc[NDBC];
    #pragma unroll
    for (int j = 0; j < NDBC; j++){
        float s = 0.f;
        #pragma unroll
        for (int t = 0; t < 3; t++) s += xi[t]*xpw[j*CI + lane + 64*t];
        dbc[j] = s;
    }
    #pragma unroll
    for (int step = 1; step < 64; step <<= 1){
        #pragma unroll
        for (int j = 0; j < NDBC; j++) dbc[j] += __shfl_xor(dbc[j], step, 64);
    }
    float BC = 0.f;
    #pragma unroll
    for (int s = 0; s < 16; s++) BC += dbc[6+s]*dbc[22+s];

    #pragma unroll
    for (int t = 0; t < 3; t++){
        int c = lane + 64*t;
        float dl = dtb[c];
        #pragma unroll
        for (int r = 0; r < DTR; r++) dl += dbc[r]*dtw[c*DTR + r];
        dl = softplusf(dl);
        gl[wave][c] = xi[t]*(dl*BC + Dp[c])*sz[t];
    }
    __syncthreads();

    for (int idx = threadIdx.x; idx < 4*CM; idx += 256){
        int pl = idx / CM, m = idx % CM;
        int pp = p0 + pl;
        int nn = pp / PX, ppx = pp % PX;
        const float* g = gl[pl];
        float s0 = 0.f, s1 = 0.f, s2 = 0.f, s3 = 0.f;
        for (int c = 0; c < CI; c += 4){
            s0 += g[c+0]*wpT[(c+0)*CM + m];
            s1 += g[c+1]*wpT[(c+1)*CM + m];
            s2 += g[c+2]*wpT[(c+2)*CM + m];
            s3 += g[c+3]*wpT[(c+3)*CM + m];
        }
        float s = (s0+s1) + (s2+s3);
        s += xres[(long)nn*nStrR + (long)m*cStrR + ppx];
        dst[(nn*CM + m)*PX + ppx] = s;
    }
}

extern "C" void kernel_launch(void* const* d_in, const int* in_sizes, int n_in,
                              void* d_out, int out_size, void* d_ws, size_t ws_size,
                              hipStream_t stream) {
    const float* x_in = (const float*)d_in[0];   // (2,96,8,24,24)
    const float* ipw  = (const float*)d_in[1];   // (2,384,96,1,3,3)
    const float* c1w  = (const float*)d_in[2];   // (2,192,1,4,1,1)
    const float* c1b  = (const float*)d_in[3];   // (2,192)
    const float* xpw  = (const float*)d_in[4];   // (2,38,192)
    const float* dtw  = (const float*)d_in[5];   // (2,192,6)
    const float* dtb  = (const float*)d_in[6];   // (2,192)
    // d_in[7] = A_log: unused at depth 0 (multiplies h[-1]=0)
    const float* Dp   = (const float*)d_in[8];   // (2,192)
    const float* opw  = (const float*)d_in[9];   // (2,96,192)
    const float* nw   = (const float*)d_in[10];  // (2,1,96,1,1,1)

    char* ws = (char*)d_ws;
    unsigned short* wQb = (unsigned short*)ws;              // 2*294912 ush = 1179648 B
    unsigned short* wRb = wQb + 2*WQB_L;                    // 2*36864 ush  = 147456 B
    float* wpT = (float*)(wRb + 2*WRB_L);                   // 2*18432 f    = 147456 B
    float* acc = wpT + 2*WPT_L;                             // 8*2*576*384 f = 14155776 B
    float* x1  = acc + (long)CSPLIT*NB*PX*CO;               // 110592 f

    // ---- prep layer 0 only
    prep1_k<<<(NPREP + 255)/256, 256, 0, stream>>>(ipw, opw, wQb, wRb, wpT);

    // ---- layer 0 conv (z=8 slice additionally preps layer-1 weights,
    //      consumed only by the later conv1/ssm1 dispatches)
    conv_k<<<dim3(NB*HP, 2, CSPLIT+1), 256, 0, stream>>>(
        x_in, 96L*8*PX, 8L*PX, nw, wQb, wRb, acc,
        ipw + IPW_L, opw + CM*CI, wQb + WQB_L, wRb + WRB_L, wpT + WPT_L);
    ssmproj_k<<<NB*PX/4, 256, 0, stream>>>(
        acc, c1w, c1b, xpw, dtw, dtb, Dp, wpT,
        x_in, 96L*8*PX, 8L*PX, x1);

    // ---- layer 1 (input x1 packed (2,96,24,24); writes final output)
    conv_k<<<dim3(NB*HP, 2, CSPLIT), 256, 0, stream>>>(
        x1, 96L*PX, (long)PX, nw + CM, wQb + WQB_L, wRb + WRB_L, acc,
        nullptr, nullptr, nullptr, nullptr, nullptr);
    ssmproj_k<<<NB*PX/4, 256, 0, stream>>>(
        acc, c1w + CI*4, c1b + CI, xpw + NDBC*CI, dtw + CI*DTR, dtb + CI, Dp + CI, wpT + WPT_L,
        x1, 96L*PX, (long)PX, (float*)d_out);
}